// Round 8
// baseline (584.697 us; speedup 1.0000x reference)
//
#include <hip/hip_runtime.h>
#include <hip/hip_fp16.h>
#include <math.h>

// ---------------------------------------------------------------------------
// TacticalGAT round 8: gather tables in FP16.  r6/r7 showed gat1 is bound on
// the gather path (both structures: 214MB L2-miss @ ~1.8TB/s = whole kernel).
// xl tables now __half (12.8/6.4 MB vs 25.6/12.8), edge attrs half4 (8B/edge).
// fp16 (not bf16): values O(6), rel err 5e-4, 100x headroom vs threshold.
// GAT kernels keep r7's wave-per-node lane=channel structure (no LDS).
// ---------------------------------------------------------------------------

union H2U { __half2 h; unsigned u; };

// ---------------- CSR build -------------------------------------------------
__global__ void hist_k(const int* __restrict__ dst, int* __restrict__ deg, int E) {
  int e = blockIdx.x * 256 + threadIdx.x;
  if (e < E) atomicAdd(&deg[dst[e]], 1);
}

__global__ void blocksum_k(const int* __restrict__ deg, int* __restrict__ bsum, int N) {
  __shared__ int s[256];
  int i = blockIdx.x * 256 + threadIdx.x;
  s[threadIdx.x] = (i < N) ? deg[i] : 0;
  __syncthreads();
  for (int off = 128; off; off >>= 1) {
    if (threadIdx.x < off) s[threadIdx.x] += s[threadIdx.x + off];
    __syncthreads();
  }
  if (threadIdx.x == 0) bsum[blockIdx.x] = s[0];
}

__global__ void scan_bsum_k(int* __restrict__ bsum, int nb) {
  __shared__ int s[256];
  int t = threadIdx.x;
  s[t] = (t < nb) ? bsum[t] : 0;
  __syncthreads();
  for (int off = 1; off < 256; off <<= 1) {
    int v = (t >= off) ? s[t - off] : 0;
    __syncthreads();
    if (t >= off) s[t] += v;
    __syncthreads();
  }
  int excl = (t == 0) ? 0 : s[t - 1];
  if (t < nb) bsum[t] = excl;
}

__global__ void writeptr_k(const int* __restrict__ deg, const int* __restrict__ bsum,
                           int* __restrict__ rowptr, int* __restrict__ cursor, int N, int E) {
  __shared__ int s[256];
  int t = threadIdx.x;
  int i = blockIdx.x * 256 + t;
  s[t] = (i < N) ? deg[i] : 0;
  __syncthreads();
  for (int off = 1; off < 256; off <<= 1) {
    int v = (t >= off) ? s[t - off] : 0;
    __syncthreads();
    if (t >= off) s[t] += v;
    __syncthreads();
  }
  int excl = bsum[blockIdx.x] + ((t == 0) ? 0 : s[t - 1]);
  if (i < N) {
    rowptr[i] = excl;
    cursor[i] = excl;
  }
  if (i == N - 1) rowptr[N] = E;
}

__global__ void fill_k(const int* __restrict__ src, const int* __restrict__ dst,
                       const float* __restrict__ eattr, int* __restrict__ cursor,
                       int* __restrict__ srcs_s, __half* __restrict__ eah, int E) {
  int e = blockIdx.x * 256 + threadIdx.x;
  if (e >= E) return;
  int d = dst[e];
  int pos = atomicAdd(&cursor[d], 1);
  srcs_s[pos] = src[e];
  H2U a, b;
  a.h = __floats2half2_rn(eattr[e * 3 + 0], eattr[e * 3 + 1]);
  b.h = __floats2half2_rn(eattr[e * 3 + 2], 0.0f);
  *(uint2*)&eah[(size_t)pos * 4] = make_uint2(a.u, b.u);
}

// ---------------- fused dual node linear, transposed-LDS --------------------
// out1 -> fp16 (gather table), out2 -> fp32.
template <int J>
__global__ __launch_bounds__(256, 3) void node_linear2t_k(
    const float* __restrict__ X,
    const float* __restrict__ W1, const float* __restrict__ b1v,
    const float* __restrict__ W2, const float* __restrict__ b2v,
    __half* __restrict__ out1, float* __restrict__ out2, int nrows) {
  constexpr int K = 128, KB = 32;
  constexpr int JG = J / 4;
  constexpr int RG = 256 / JG;
  constexpr int RB = RG * 4;
  constexpr int XP = RB + 4;
  constexpr int WP = J + 4;
  __shared__ float sXT[K][XP];
  __shared__ float sW1T[KB][WP];
  __shared__ float sW2T[KB][WP];

  int tid = threadIdx.x;
  int n0 = blockIdx.x * RB;

  {
    int r = tid & (RB - 1);
    int kq0 = tid / RB;
    constexpr int KQS = 256 / RB;
    int n = n0 + r;
    bool ok = n < nrows;
    for (int kq = kq0; kq < K / 4; kq += KQS) {
      float4 v = ok ? *(const float4*)&X[(size_t)n * K + kq * 4]
                    : make_float4(0.f, 0.f, 0.f, 0.f);
      sXT[kq * 4 + 0][r] = v.x;
      sXT[kq * 4 + 1][r] = v.y;
      sXT[kq * 4 + 2][r] = v.z;
      sXT[kq * 4 + 3][r] = v.w;
    }
  }

  int jg = tid % JG;
  int rg = tid / JG;
  float acc1[4][4] = {}, acc2[4][4] = {};

  for (int kb = 0; kb < K / KB; ++kb) {
    __syncthreads();
    {
      int j = tid & (J - 1);
      int kq0 = tid / J;
      constexpr int KQS = 256 / J;
      for (int kq = kq0; kq < KB / 4; kq += KQS) {
        float4 v1 = *(const float4*)&W1[(size_t)j * K + kb * KB + kq * 4];
        float4 v2 = *(const float4*)&W2[(size_t)j * K + kb * KB + kq * 4];
        sW1T[kq * 4 + 0][j] = v1.x;
        sW1T[kq * 4 + 1][j] = v1.y;
        sW1T[kq * 4 + 2][j] = v1.z;
        sW1T[kq * 4 + 3][j] = v1.w;
        sW2T[kq * 4 + 0][j] = v2.x;
        sW2T[kq * 4 + 1][j] = v2.y;
        sW2T[kq * 4 + 2][j] = v2.z;
        sW2T[kq * 4 + 3][j] = v2.w;
      }
    }
    __syncthreads();
#pragma unroll
    for (int k = 0; k < KB; ++k) {
      float4 xv = *(const float4*)&sXT[kb * KB + k][rg * 4];
      float4 w1 = *(const float4*)&sW1T[k][jg * 4];
      float4 w2 = *(const float4*)&sW2T[k][jg * 4];
      float xs[4] = {xv.x, xv.y, xv.z, xv.w};
      float w1s[4] = {w1.x, w1.y, w1.z, w1.w};
      float w2s[4] = {w2.x, w2.y, w2.z, w2.w};
#pragma unroll
      for (int i = 0; i < 4; ++i)
#pragma unroll
        for (int q = 0; q < 4; ++q) {
          acc1[i][q] = fmaf(xs[i], w1s[q], acc1[i][q]);
          acc2[i][q] = fmaf(xs[i], w2s[q], acc2[i][q]);
        }
    }
  }

  float4 bv1 = *(const float4*)&b1v[jg * 4];
  float4 bv2 = *(const float4*)&b2v[jg * 4];
#pragma unroll
  for (int i = 0; i < 4; ++i) {
    int n = n0 + rg * 4 + i;
    if (n < nrows) {
      H2U a, b;
      a.h = __floats2half2_rn(acc1[i][0] + bv1.x, acc1[i][1] + bv1.y);
      b.h = __floats2half2_rn(acc1[i][2] + bv1.z, acc1[i][3] + bv1.w);
      *(uint2*)&out1[(size_t)n * J + jg * 4] = make_uint2(a.u, b.u);
      float4 o2 = make_float4(acc2[i][0] + bv2.x, acc2[i][1] + bv2.y,
                              acc2[i][2] + bv2.z, acc2[i][3] + bv2.w);
      *(float4*)&out2[(size_t)n * J + jg * 4] = o2;
    }
  }
}

__device__ __forceinline__ float3 load_ea(const __half* eah, size_t e) {
  uint2 p = *(const uint2*)&eah[e * 4];
  H2U a, b;
  a.u = p.x; b.u = p.y;
  float2 f01 = __half22float2(a.h);
  float2 f23 = __half22float2(b.h);
  return make_float3(f01.x, f01.y, f23.x);
}

// ---------------- fused GATv2 layer 1 (H=4, C=32, concat) -------------------
// wave per node, lane = channel pair c0=2*lane; fp16 row gather (256B/edge).
__global__ __launch_bounds__(256) void gat1_fused_k(
    const int* __restrict__ rowptr, const int* __restrict__ srcs,
    const __half* __restrict__ eah, const __half* __restrict__ xlh,
    const float* __restrict__ xr, const float* __restrict__ We,
    const float* __restrict__ att, const float* __restrict__ bias,
    float* __restrict__ out, int N) {
  constexpr int CH = 8;
  int lane = threadIdx.x & 63;
  int n = __builtin_amdgcn_readfirstlane((int)((blockIdx.x * 256 + threadIdx.x) >> 6));
  if (n >= N) return;
  const __half2* xl2p = (const __half2*)xlh;  // row stride 64 half2
  int c0 = 2 * lane;
  float4 w0 = make_float4(We[c0 * 3], We[c0 * 3 + 1], We[c0 * 3 + 2], att[c0]);
  float4 w1 = make_float4(We[c0 * 3 + 3], We[c0 * 3 + 4], We[c0 * 3 + 5], att[c0 + 1]);
  float2 xrv = *(const float2*)&xr[(size_t)n * 128 + c0];
  int beg = rowptr[n], end = rowptr[n + 1];

  float acc0 = 0.f, acc1 = 0.f, den = 0.f;
  float es0 = 0.f, es1 = 0.f, es2 = 0.f;

  __half2 rA[CH], rB[CH];
  float3 eaA[CH], eaB[CH];
  int sN[CH];

#pragma unroll
  for (int j = 0; j < CH; ++j)
    if (beg + j < end) {
      int s = srcs[beg + j];
      rA[j] = xl2p[(size_t)s * 64 + lane];
      eaA[j] = load_ea(eah, beg + j);
    }
#pragma unroll
  for (int j = 0; j < CH; ++j)
    if (beg + CH + j < end) sN[j] = srcs[beg + CH + j];

  auto compute = [&](int base, __half2* r, float3* ea) {
#pragma unroll
    for (int j = 0; j < CH; ++j)
      if (base + j < end) {
        float3 e = ea[j];
        es0 += e.x; es1 += e.y; es2 += e.z;
        float2 rf = __half22float2(r[j]);
        float m0 = rf.x + xrv.x + e.x * w0.x + e.y * w0.y + e.z * w0.z;
        float m1 = rf.y + xrv.y + e.x * w1.x + e.y * w1.y + e.z * w1.z;
        m0 = fmaxf(m0, 0.2f * m0);
        m1 = fmaxf(m1, 0.2f * m1);
        float v = fmaf(m0, w0.w, m1 * w1.w);
        v += __shfl_xor(v, 1);
        v += __shfl_xor(v, 2);
        v += __shfl_xor(v, 4);
        v += __shfl_xor(v, 8);
        float ex = __expf(v);
        den += ex;
        acc0 = fmaf(ex, rf.x, acc0);
        acc1 = fmaf(ex, rf.y, acc1);
      }
  };

  int base = beg;
  while (true) {
    {
      int nb = base + CH;
      if (nb < end) {
#pragma unroll
        for (int j = 0; j < CH; ++j)
          if (nb + j < end) {
            rB[j] = xl2p[(size_t)sN[j] * 64 + lane];
            eaB[j] = load_ea(eah, nb + j);
          }
#pragma unroll
        for (int j = 0; j < CH; ++j)
          if (nb + CH + j < end) sN[j] = srcs[nb + CH + j];
      }
      compute(base, rA, eaA);
      base = nb;
      if (base >= end) break;
    }
    {
      int nb = base + CH;
      if (nb < end) {
#pragma unroll
        for (int j = 0; j < CH; ++j)
          if (nb + j < end) {
            rA[j] = xl2p[(size_t)sN[j] * 64 + lane];
            eaA[j] = load_ea(eah, nb + j);
          }
#pragma unroll
        for (int j = 0; j < CH; ++j)
          if (nb + CH + j < end) sN[j] = srcs[nb + CH + j];
      }
      compute(base, rB, eaB);
      base = nb;
      if (base >= end) break;
    }
  }

  // self loop (attr = mean of incoming)
  float invd = 1.0f / fmaxf((float)(end - beg), 1.0f);
  es0 *= invd; es1 *= invd; es2 *= invd;
  float2 xls = __half22float2(xl2p[(size_t)n * 64 + lane]);
  float m0 = xls.x + xrv.x + es0 * w0.x + es1 * w0.y + es2 * w0.z;
  float m1 = xls.y + xrv.y + es0 * w1.x + es1 * w1.y + es2 * w1.z;
  m0 = fmaxf(m0, 0.2f * m0);
  m1 = fmaxf(m1, 0.2f * m1);
  float v = fmaf(m0, w0.w, m1 * w1.w);
  v += __shfl_xor(v, 1);
  v += __shfl_xor(v, 2);
  v += __shfl_xor(v, 4);
  v += __shfl_xor(v, 8);
  float ex = __expf(v);
  den += ex;
  acc0 = fmaf(ex, xls.x, acc0);
  acc1 = fmaf(ex, xls.y, acc1);

  float o0 = acc0 / den + bias[c0];
  float o1 = acc1 / den + bias[c0 + 1];
  o0 = o0 > 0.f ? o0 : __expf(o0) - 1.0f;  // ELU
  o1 = o1 > 0.f ? o1 : __expf(o1) - 1.0f;
  *(float2*)&out[(size_t)n * 128 + c0] = make_float2(o0, o1);
}

// ---------------- fused GATv2 layer 2 (H=1, C=64, mean) ---------------------
__global__ __launch_bounds__(256) void gat2_fused_k(
    const int* __restrict__ rowptr, const int* __restrict__ srcs,
    const __half* __restrict__ eah, const __half* __restrict__ xlh,
    const float* __restrict__ xr, const float* __restrict__ We,
    const float* __restrict__ att, const float* __restrict__ bias,
    float* __restrict__ out, int N) {
  constexpr int CH = 8;
  int lane = threadIdx.x & 63;
  int n = __builtin_amdgcn_readfirstlane((int)((blockIdx.x * 256 + threadIdx.x) >> 6));
  if (n >= N) return;
  float4 w = make_float4(We[lane * 3], We[lane * 3 + 1], We[lane * 3 + 2], att[lane]);
  float xrv = xr[(size_t)n * 64 + lane];
  int beg = rowptr[n], end = rowptr[n + 1];

  float acc = 0.f, den = 0.f;
  float es0 = 0.f, es1 = 0.f, es2 = 0.f;

  __half rA[CH], rB[CH];
  float3 eaA[CH], eaB[CH];
  int sN[CH];

#pragma unroll
  for (int j = 0; j < CH; ++j)
    if (beg + j < end) {
      int s = srcs[beg + j];
      rA[j] = xlh[(size_t)s * 64 + lane];
      eaA[j] = load_ea(eah, beg + j);
    }
#pragma unroll
  for (int j = 0; j < CH; ++j)
    if (beg + CH + j < end) sN[j] = srcs[beg + CH + j];

  auto compute = [&](int base, __half* r, float3* ea) {
#pragma unroll
    for (int j = 0; j < CH; ++j)
      if (base + j < end) {
        float3 e = ea[j];
        es0 += e.x; es1 += e.y; es2 += e.z;
        float rf = __half2float(r[j]);
        float m = rf + xrv + e.x * w.x + e.y * w.y + e.z * w.z;
        m = fmaxf(m, 0.2f * m);
        float v = m * w.w;
        v += __shfl_xor(v, 1);
        v += __shfl_xor(v, 2);
        v += __shfl_xor(v, 4);
        v += __shfl_xor(v, 8);
        v += __shfl_xor(v, 16);
        v += __shfl_xor(v, 32);
        float ex = __expf(v);
        den += ex;
        acc = fmaf(ex, rf, acc);
      }
  };

  int base = beg;
  while (true) {
    {
      int nb = base + CH;
      if (nb < end) {
#pragma unroll
        for (int j = 0; j < CH; ++j)
          if (nb + j < end) {
            rB[j] = xlh[(size_t)sN[j] * 64 + lane];
            eaB[j] = load_ea(eah, nb + j);
          }
#pragma unroll
        for (int j = 0; j < CH; ++j)
          if (nb + CH + j < end) sN[j] = srcs[nb + CH + j];
      }
      compute(base, rA, eaA);
      base = nb;
      if (base >= end) break;
    }
    {
      int nb = base + CH;
      if (nb < end) {
#pragma unroll
        for (int j = 0; j < CH; ++j)
          if (nb + j < end) {
            rA[j] = xlh[(size_t)sN[j] * 64 + lane];
            eaA[j] = load_ea(eah, nb + j);
          }
#pragma unroll
        for (int j = 0; j < CH; ++j)
          if (nb + CH + j < end) sN[j] = srcs[nb + CH + j];
      }
      compute(base, rB, eaB);
      base = nb;
      if (base >= end) break;
    }
  }

  float invd = 1.0f / fmaxf((float)(end - beg), 1.0f);
  es0 *= invd; es1 *= invd; es2 *= invd;
  float xls = __half2float(xlh[(size_t)n * 64 + lane]);
  float m = xls + xrv + es0 * w.x + es1 * w.y + es2 * w.z;
  m = fmaxf(m, 0.2f * m);
  float v = m * w.w;
  v += __shfl_xor(v, 1);
  v += __shfl_xor(v, 2);
  v += __shfl_xor(v, 4);
  v += __shfl_xor(v, 8);
  v += __shfl_xor(v, 16);
  v += __shfl_xor(v, 32);
  float ex = __expf(v);
  den += ex;
  acc = fmaf(ex, xls, acc);

  float o = acc / den + bias[lane];
  o = o > 0.f ? o : __expf(o) - 1.0f;  // ELU
  out[(size_t)n * 64 + lane] = o;
}

// ---------------- graph boundaries (batch is sorted) ------------------------
__global__ void gbound_k(const int* __restrict__ batch, int* __restrict__ gstart,
                         int N, int G) {
  int g = blockIdx.x * 256 + threadIdx.x;
  if (g > G) return;
  int lo = 0, hi = N;
  while (lo < hi) {
    int mid = (lo + hi) >> 1;
    if (batch[mid] < g) lo = mid + 1;
    else hi = mid;
  }
  gstart[g] = lo;
}

// ---------------- fused mean-pool + MLP head (block per graph) --------------
__global__ void final_mlp_k(const float* __restrict__ h2, const int* __restrict__ gstart,
                            const float* __restrict__ u, const float* __restrict__ W1,
                            const float* __restrict__ b1, const float* __restrict__ Wh,
                            const float* __restrict__ bh, float* __restrict__ out) {
  __shared__ float feat[65];
  __shared__ float z[32];
  int g = blockIdx.x;
  int t = threadIdx.x;  // 64 threads
  int lo = gstart[g], hi = gstart[g + 1];
  float a = 0.f;
  for (int nn = lo; nn < hi; ++nn) a += h2[(size_t)nn * 64 + t];
  float inv = 1.0f / fmaxf((float)(hi - lo), 1.0f);
  feat[t] = a * inv;
  if (t == 0) feat[64] = u[g];
  __syncthreads();
  if (t < 32) {
    float s = b1[t];
    for (int k = 0; k < 65; ++k) s += feat[k] * W1[t * 65 + k];
    z[t] = fmaxf(s, 0.0f);
  }
  __syncthreads();
  if (t < 10) {
    float s = bh[t];
    for (int k = 0; k < 32; ++k) s += z[k] * Wh[t * 32 + k];
    out[g * 10 + t] = s;
  }
}

// ---------------------------------------------------------------------------
extern "C" void kernel_launch(void* const* d_in, const int* in_sizes, int n_in,
                              void* d_out, int out_size, void* d_ws, size_t ws_size,
                              hipStream_t stream) {
  const float* x      = (const float*)d_in[0];
  const int*   eidx   = (const int*)d_in[1];
  const float* eattr  = (const float*)d_in[2];
  const int*   batch  = (const int*)d_in[3];
  const float* u      = (const float*)d_in[4];
  const float* Wl1    = (const float*)d_in[5];
  const float* bl1    = (const float*)d_in[6];
  const float* Wr1    = (const float*)d_in[7];
  const float* br1    = (const float*)d_in[8];
  const float* We1    = (const float*)d_in[9];
  const float* att1   = (const float*)d_in[10];
  const float* b1     = (const float*)d_in[11];
  const float* Wl2    = (const float*)d_in[12];
  const float* bl2    = (const float*)d_in[13];
  const float* Wr2    = (const float*)d_in[14];
  const float* br2    = (const float*)d_in[15];
  const float* We2    = (const float*)d_in[16];
  const float* att2   = (const float*)d_in[17];
  const float* b2     = (const float*)d_in[18];
  const float* W_lin1 = (const float*)d_in[19];
  const float* b_lin1 = (const float*)d_in[20];
  const float* W_head = (const float*)d_in[21];
  const float* b_head = (const float*)d_in[22];

  const int N = in_sizes[0] / 128;
  const int E = in_sizes[1] / 2;
  const int G = in_sizes[4];
  const int* srcp = eidx;
  const int* dstp = eidx + E;

  // ---- workspace layout ----
  __half* bufh = (__half*)d_ws;                     // xl1 half (N*128) -> xl2 half (N*64)
  float* buf2 = (float*)(bufh + (size_t)N * 128);   // xr1 (N*128) -> xr2 (N*64)
  float* buf3 = buf2 + (size_t)N * 128;             // h1 (N*128) -> h2 (N*64)
  __half* eah = (__half*)(buf3 + (size_t)N * 128);  // E * half4 (8B/edge)
  int* srcs_s = (int*)(eah + (size_t)E * 4);        // E sorted src ids
  int* deg    = srcs_s + E;                         // N
  int* rowptr = deg + N;                            // N+1
  int* cursor = rowptr + N + 1;                     // N
  int* bsum   = cursor + N;                         // 256
  int* gstart = bsum + 256;                         // G+1

  const int nb = (N + 255) / 256;

  // ---- CSR build (sort edges by dst) ----
  hipMemsetAsync(deg, 0, sizeof(int) * (size_t)N, stream);
  hist_k<<<(E + 255) / 256, 256, 0, stream>>>(dstp, deg, E);
  blocksum_k<<<nb, 256, 0, stream>>>(deg, bsum, N);
  scan_bsum_k<<<1, 256, 0, stream>>>(bsum, nb);
  writeptr_k<<<nb, 256, 0, stream>>>(deg, bsum, rowptr, cursor, N, E);
  fill_k<<<(E + 255) / 256, 256, 0, stream>>>(srcp, dstp, eattr, cursor, srcs_s, eah, E);
  gbound_k<<<(G + 256) / 256, 256, 0, stream>>>(batch, gstart, N, G);

  // ---- layer 1 ----
  node_linear2t_k<128><<<(N + 31) / 32, 256, 0, stream>>>(x, Wl1, bl1, Wr1, br1,
                                                          bufh, buf2, N);
  gat1_fused_k<<<(N + 3) / 4, 256, 0, stream>>>(rowptr, srcs_s, eah, bufh, buf2,
                                                We1, att1, b1, buf3, N);

  // ---- layer 2 ----
  node_linear2t_k<64><<<(N + 63) / 64, 256, 0, stream>>>(buf3, Wl2, bl2, Wr2, br2,
                                                         bufh, buf2, N);
  gat2_fused_k<<<(N + 3) / 4, 256, 0, stream>>>(rowptr, srcs_s, eah, bufh, buf2,
                                                We2, att2, b2, buf3, N);

  // ---- fused pool + head ----
  final_mlp_k<<<G, 64, 0, stream>>>(buf3, gstart, u, W_lin1, b_lin1, W_head, b_head,
                                    (float*)d_out);
}

// Round 9
// 500.235 us; speedup vs baseline: 1.1688x; 1.1688x over previous
//
#include <hip/hip_runtime.h>
#include <hip/hip_fp16.h>
#include <math.h>

// ---------------------------------------------------------------------------
// TacticalGAT round 9: gat2 restructured -- 32-lane edge groups (2 ch/lane,
// 5-level reduce, 2 edges/wave in flight), branchless chunked main loops
// (r8's per-edge uniform guards blocked cross-edge ILP), persistent
// grid-stride waves (32 waves/CU resident; r8 measured 35% occupancy).
// fp16 gather tables kept from r8 (gat1 fetch halved).
// ---------------------------------------------------------------------------

union H2U { __half2 h; unsigned u; };

// ---------------- CSR build -------------------------------------------------
__global__ void hist_k(const int* __restrict__ dst, int* __restrict__ deg, int E) {
  int e = blockIdx.x * 256 + threadIdx.x;
  if (e < E) atomicAdd(&deg[dst[e]], 1);
}

__global__ void blocksum_k(const int* __restrict__ deg, int* __restrict__ bsum, int N) {
  __shared__ int s[256];
  int i = blockIdx.x * 256 + threadIdx.x;
  s[threadIdx.x] = (i < N) ? deg[i] : 0;
  __syncthreads();
  for (int off = 128; off; off >>= 1) {
    if (threadIdx.x < off) s[threadIdx.x] += s[threadIdx.x + off];
    __syncthreads();
  }
  if (threadIdx.x == 0) bsum[blockIdx.x] = s[0];
}

__global__ void scan_bsum_k(int* __restrict__ bsum, int nb) {
  __shared__ int s[256];
  int t = threadIdx.x;
  s[t] = (t < nb) ? bsum[t] : 0;
  __syncthreads();
  for (int off = 1; off < 256; off <<= 1) {
    int v = (t >= off) ? s[t - off] : 0;
    __syncthreads();
    if (t >= off) s[t] += v;
    __syncthreads();
  }
  int excl = (t == 0) ? 0 : s[t - 1];
  if (t < nb) bsum[t] = excl;
}

__global__ void writeptr_k(const int* __restrict__ deg, const int* __restrict__ bsum,
                           int* __restrict__ rowptr, int* __restrict__ cursor, int N, int E) {
  __shared__ int s[256];
  int t = threadIdx.x;
  int i = blockIdx.x * 256 + t;
  s[t] = (i < N) ? deg[i] : 0;
  __syncthreads();
  for (int off = 1; off < 256; off <<= 1) {
    int v = (t >= off) ? s[t - off] : 0;
    __syncthreads();
    if (t >= off) s[t] += v;
    __syncthreads();
  }
  int excl = bsum[blockIdx.x] + ((t == 0) ? 0 : s[t - 1]);
  if (i < N) {
    rowptr[i] = excl;
    cursor[i] = excl;
  }
  if (i == N - 1) rowptr[N] = E;
}

__global__ void fill_k(const int* __restrict__ src, const int* __restrict__ dst,
                       const float* __restrict__ eattr, int* __restrict__ cursor,
                       int* __restrict__ srcs_s, __half* __restrict__ eah, int E) {
  int e = blockIdx.x * 256 + threadIdx.x;
  if (e >= E) return;
  int d = dst[e];
  int pos = atomicAdd(&cursor[d], 1);
  srcs_s[pos] = src[e];
  H2U a, b;
  a.h = __floats2half2_rn(eattr[e * 3 + 0], eattr[e * 3 + 1]);
  b.h = __floats2half2_rn(eattr[e * 3 + 2], 0.0f);
  *(uint2*)&eah[(size_t)pos * 4] = make_uint2(a.u, b.u);
}

// ---------------- fused dual node linear, transposed-LDS --------------------
template <int J>
__global__ __launch_bounds__(256, 3) void node_linear2t_k(
    const float* __restrict__ X,
    const float* __restrict__ W1, const float* __restrict__ b1v,
    const float* __restrict__ W2, const float* __restrict__ b2v,
    __half* __restrict__ out1, float* __restrict__ out2, int nrows) {
  constexpr int K = 128, KB = 32;
  constexpr int JG = J / 4;
  constexpr int RG = 256 / JG;
  constexpr int RB = RG * 4;
  constexpr int XP = RB + 4;
  constexpr int WP = J + 4;
  __shared__ float sXT[K][XP];
  __shared__ float sW1T[KB][WP];
  __shared__ float sW2T[KB][WP];

  int tid = threadIdx.x;
  int n0 = blockIdx.x * RB;

  {
    int r = tid & (RB - 1);
    int kq0 = tid / RB;
    constexpr int KQS = 256 / RB;
    int n = n0 + r;
    bool ok = n < nrows;
    for (int kq = kq0; kq < K / 4; kq += KQS) {
      float4 v = ok ? *(const float4*)&X[(size_t)n * K + kq * 4]
                    : make_float4(0.f, 0.f, 0.f, 0.f);
      sXT[kq * 4 + 0][r] = v.x;
      sXT[kq * 4 + 1][r] = v.y;
      sXT[kq * 4 + 2][r] = v.z;
      sXT[kq * 4 + 3][r] = v.w;
    }
  }

  int jg = tid % JG;
  int rg = tid / JG;
  float acc1[4][4] = {}, acc2[4][4] = {};

  for (int kb = 0; kb < K / KB; ++kb) {
    __syncthreads();
    {
      int j = tid & (J - 1);
      int kq0 = tid / J;
      constexpr int KQS = 256 / J;
      for (int kq = kq0; kq < KB / 4; kq += KQS) {
        float4 v1 = *(const float4*)&W1[(size_t)j * K + kb * KB + kq * 4];
        float4 v2 = *(const float4*)&W2[(size_t)j * K + kb * KB + kq * 4];
        sW1T[kq * 4 + 0][j] = v1.x;
        sW1T[kq * 4 + 1][j] = v1.y;
        sW1T[kq * 4 + 2][j] = v1.z;
        sW1T[kq * 4 + 3][j] = v1.w;
        sW2T[kq * 4 + 0][j] = v2.x;
        sW2T[kq * 4 + 1][j] = v2.y;
        sW2T[kq * 4 + 2][j] = v2.z;
        sW2T[kq * 4 + 3][j] = v2.w;
      }
    }
    __syncthreads();
#pragma unroll
    for (int k = 0; k < KB; ++k) {
      float4 xv = *(const float4*)&sXT[kb * KB + k][rg * 4];
      float4 w1 = *(const float4*)&sW1T[k][jg * 4];
      float4 w2 = *(const float4*)&sW2T[k][jg * 4];
      float xs[4] = {xv.x, xv.y, xv.z, xv.w};
      float w1s[4] = {w1.x, w1.y, w1.z, w1.w};
      float w2s[4] = {w2.x, w2.y, w2.z, w2.w};
#pragma unroll
      for (int i = 0; i < 4; ++i)
#pragma unroll
        for (int q = 0; q < 4; ++q) {
          acc1[i][q] = fmaf(xs[i], w1s[q], acc1[i][q]);
          acc2[i][q] = fmaf(xs[i], w2s[q], acc2[i][q]);
        }
    }
  }

  float4 bv1 = *(const float4*)&b1v[jg * 4];
  float4 bv2 = *(const float4*)&b2v[jg * 4];
#pragma unroll
  for (int i = 0; i < 4; ++i) {
    int n = n0 + rg * 4 + i;
    if (n < nrows) {
      H2U a, b;
      a.h = __floats2half2_rn(acc1[i][0] + bv1.x, acc1[i][1] + bv1.y);
      b.h = __floats2half2_rn(acc1[i][2] + bv1.z, acc1[i][3] + bv1.w);
      *(uint2*)&out1[(size_t)n * J + jg * 4] = make_uint2(a.u, b.u);
      float4 o2 = make_float4(acc2[i][0] + bv2.x, acc2[i][1] + bv2.y,
                              acc2[i][2] + bv2.z, acc2[i][3] + bv2.w);
      *(float4*)&out2[(size_t)n * J + jg * 4] = o2;
    }
  }
}

__device__ __forceinline__ float3 load_ea(const __half* eah, size_t e) {
  uint2 p = *(const uint2*)&eah[e * 4];
  H2U a, b;
  a.u = p.x; b.u = p.y;
  float2 f01 = __half22float2(a.h);
  float2 f23 = __half22float2(b.h);
  return make_float3(f01.x, f01.y, f23.x);
}

// ---------------- fused GATv2 layer 1 (H=4, C=32, concat) -------------------
// persistent wave per node (grid-stride); lane = channel pair c0 = 2*lane;
// 4-level reduce within 16-lane head group; branchless CH-chunk main loop.
__global__ __launch_bounds__(256) void gat1_fused_k(
    const int* __restrict__ rowptr, const int* __restrict__ srcs,
    const __half* __restrict__ eah, const __half* __restrict__ xlh,
    const float* __restrict__ xr, const float* __restrict__ We,
    const float* __restrict__ att, const float* __restrict__ bias,
    float* __restrict__ out, int N) {
  constexpr int CH = 8;
  int lane = threadIdx.x & 63;
  int wave0 = __builtin_amdgcn_readfirstlane(
      (int)((blockIdx.x * 256 + threadIdx.x) >> 6));
  int nwaves = gridDim.x * 4;
  const __half2* xl2p = (const __half2*)xlh;
  int c0 = 2 * lane;
  float4 w0 = make_float4(We[c0 * 3], We[c0 * 3 + 1], We[c0 * 3 + 2], att[c0]);
  float4 w1 = make_float4(We[c0 * 3 + 3], We[c0 * 3 + 4], We[c0 * 3 + 5], att[c0 + 1]);
  float2 bv = make_float2(bias[c0], bias[c0 + 1]);

  for (int n = wave0; n < N; n += nwaves) {
    float2 xrv = *(const float2*)&xr[(size_t)n * 128 + c0];
    int beg = rowptr[n], end = rowptr[n + 1];
    int deg = end - beg;

    float acc0 = 0.f, acc1 = 0.f, den = 0.f;
    float es0 = 0.f, es1 = 0.f, es2 = 0.f;

    int nfull = deg / CH;
    for (int ch = 0; ch < nfull; ++ch) {
      int b = beg + ch * CH;
      int sC[CH];
#pragma unroll
      for (int j = 0; j < CH; ++j) sC[j] = srcs[b + j];
      __half2 r_[CH];
      float3 ea_[CH];
#pragma unroll
      for (int j = 0; j < CH; ++j) {
        r_[j] = xl2p[(size_t)sC[j] * 64 + lane];
        ea_[j] = load_ea(eah, b + j);
      }
#pragma unroll
      for (int j = 0; j < CH; ++j) {
        float3 e = ea_[j];
        es0 += e.x; es1 += e.y; es2 += e.z;
        float2 rf = __half22float2(r_[j]);
        float m0 = rf.x + xrv.x + e.x * w0.x + e.y * w0.y + e.z * w0.z;
        float m1 = rf.y + xrv.y + e.x * w1.x + e.y * w1.y + e.z * w1.z;
        m0 = fmaxf(m0, 0.2f * m0);
        m1 = fmaxf(m1, 0.2f * m1);
        float v = fmaf(m0, w0.w, m1 * w1.w);
        v += __shfl_xor(v, 1);
        v += __shfl_xor(v, 2);
        v += __shfl_xor(v, 4);
        v += __shfl_xor(v, 8);
        float ex = __expf(v);
        den += ex;
        acc0 = fmaf(ex, rf.x, acc0);
        acc1 = fmaf(ex, rf.y, acc1);
      }
    }
    // tail (guarded, < CH edges)
    {
      int b = beg + nfull * CH;
#pragma unroll
      for (int j = 0; j < CH; ++j) {
        int gi = b + j;
        bool valid = gi < end;
        int s = valid ? srcs[gi] : n;
        float3 e = valid ? load_ea(eah, gi) : make_float3(0.f, 0.f, 0.f);
        float2 rf = __half22float2(xl2p[(size_t)s * 64 + lane]);
        es0 += e.x; es1 += e.y; es2 += e.z;
        float m0 = rf.x + xrv.x + e.x * w0.x + e.y * w0.y + e.z * w0.z;
        float m1 = rf.y + xrv.y + e.x * w1.x + e.y * w1.y + e.z * w1.z;
        m0 = fmaxf(m0, 0.2f * m0);
        m1 = fmaxf(m1, 0.2f * m1);
        float v = fmaf(m0, w0.w, m1 * w1.w);
        v += __shfl_xor(v, 1);
        v += __shfl_xor(v, 2);
        v += __shfl_xor(v, 4);
        v += __shfl_xor(v, 8);
        float ex = valid ? __expf(v) : 0.f;
        den += ex;
        acc0 = fmaf(ex, rf.x, acc0);
        acc1 = fmaf(ex, rf.y, acc1);
      }
    }

    // self loop (attr = mean of incoming)
    float invd = 1.0f / fmaxf((float)deg, 1.0f);
    float t0 = es0 * invd, t1 = es1 * invd, t2 = es2 * invd;
    float2 xls = __half22float2(xl2p[(size_t)n * 64 + lane]);
    float m0 = xls.x + xrv.x + t0 * w0.x + t1 * w0.y + t2 * w0.z;
    float m1 = xls.y + xrv.y + t0 * w1.x + t1 * w1.y + t2 * w1.z;
    m0 = fmaxf(m0, 0.2f * m0);
    m1 = fmaxf(m1, 0.2f * m1);
    float v = fmaf(m0, w0.w, m1 * w1.w);
    v += __shfl_xor(v, 1);
    v += __shfl_xor(v, 2);
    v += __shfl_xor(v, 4);
    v += __shfl_xor(v, 8);
    float ex = __expf(v);
    den += ex;
    acc0 = fmaf(ex, xls.x, acc0);
    acc1 = fmaf(ex, xls.y, acc1);

    float o0 = acc0 / den + bv.x;
    float o1 = acc1 / den + bv.y;
    o0 = o0 > 0.f ? o0 : __expf(o0) - 1.0f;  // ELU
    o1 = o1 > 0.f ? o1 : __expf(o1) - 1.0f;
    *(float2*)&out[(size_t)n * 128 + c0] = make_float2(o0, o1);
  }
}

// ---------------- fused GATv2 layer 2 (H=1, C=64, mean) ---------------------
// persistent wave per node; 32-lane edge groups (grp = lane>>5), 2 ch/lane,
// 5-level reduce within group covers all 64 channels; 2 edges/wave in flight.
__global__ __launch_bounds__(256) void gat2_fused_k(
    const int* __restrict__ rowptr, const int* __restrict__ srcs,
    const __half* __restrict__ eah, const __half* __restrict__ xlh,
    const float* __restrict__ xr, const float* __restrict__ We,
    const float* __restrict__ att, const float* __restrict__ bias,
    float* __restrict__ out, int N) {
  constexpr int CP = 4;  // edge pairs per chunk -> 8 edges
  int lane = threadIdx.x & 63;
  int wave0 = __builtin_amdgcn_readfirstlane(
      (int)((blockIdx.x * 256 + threadIdx.x) >> 6));
  int nwaves = gridDim.x * 4;
  int sub = lane & 31, grp = lane >> 5;
  int c0 = 2 * sub;
  const __half2* xl2p = (const __half2*)xlh;  // row stride 32 half2
  float4 w0 = make_float4(We[c0 * 3], We[c0 * 3 + 1], We[c0 * 3 + 2], att[c0]);
  float4 w1 = make_float4(We[c0 * 3 + 3], We[c0 * 3 + 4], We[c0 * 3 + 5], att[c0 + 1]);
  float2 bv = make_float2(bias[c0], bias[c0 + 1]);

  for (int n = wave0; n < N; n += nwaves) {
    float2 xrv = *(const float2*)&xr[(size_t)n * 64 + c0];
    int beg = rowptr[n], end = rowptr[n + 1];
    int deg = end - beg;

    float acc0 = 0.f, acc1 = 0.f, den = 0.f;
    float es0 = 0.f, es1 = 0.f, es2 = 0.f;

    int nfull = deg / (2 * CP);
    int b = beg + grp;
    for (int ch = 0; ch < nfull; ++ch) {
      int sC[CP];
      float3 ea_[CP];
      __half2 r_[CP];
#pragma unroll
      for (int j = 0; j < CP; ++j) {
        int gi = b + 2 * j;
        sC[j] = srcs[gi];
        ea_[j] = load_ea(eah, gi);
      }
#pragma unroll
      for (int j = 0; j < CP; ++j) r_[j] = xl2p[(size_t)sC[j] * 32 + sub];
#pragma unroll
      for (int j = 0; j < CP; ++j) {
        float3 e = ea_[j];
        es0 += e.x; es1 += e.y; es2 += e.z;
        float2 rf = __half22float2(r_[j]);
        float m0 = rf.x + xrv.x + e.x * w0.x + e.y * w0.y + e.z * w0.z;
        float m1 = rf.y + xrv.y + e.x * w1.x + e.y * w1.y + e.z * w1.z;
        m0 = fmaxf(m0, 0.2f * m0);
        m1 = fmaxf(m1, 0.2f * m1);
        float v = fmaf(m0, w0.w, m1 * w1.w);
        v += __shfl_xor(v, 1);
        v += __shfl_xor(v, 2);
        v += __shfl_xor(v, 4);
        v += __shfl_xor(v, 8);
        v += __shfl_xor(v, 16);
        float ex = __expf(v);
        den += ex;
        acc0 = fmaf(ex, rf.x, acc0);
        acc1 = fmaf(ex, rf.y, acc1);
      }
      b += 2 * CP;
    }
    // tail (guarded, < 2*CP edges)
    {
      int tb = beg + nfull * 2 * CP;
#pragma unroll
      for (int j = 0; j < CP; ++j) {
        int gi = tb + 2 * j + grp;
        bool valid = gi < end;
        int s = valid ? srcs[gi] : n;
        float3 e = valid ? load_ea(eah, gi) : make_float3(0.f, 0.f, 0.f);
        float2 rf = __half22float2(xl2p[(size_t)s * 32 + sub]);
        es0 += e.x; es1 += e.y; es2 += e.z;
        float m0 = rf.x + xrv.x + e.x * w0.x + e.y * w0.y + e.z * w0.z;
        float m1 = rf.y + xrv.y + e.x * w1.x + e.y * w1.y + e.z * w1.z;
        m0 = fmaxf(m0, 0.2f * m0);
        m1 = fmaxf(m1, 0.2f * m1);
        float v = fmaf(m0, w0.w, m1 * w1.w);
        v += __shfl_xor(v, 1);
        v += __shfl_xor(v, 2);
        v += __shfl_xor(v, 4);
        v += __shfl_xor(v, 8);
        v += __shfl_xor(v, 16);
        float ex = valid ? __expf(v) : 0.f;
        den += ex;
        acc0 = fmaf(ex, rf.x, acc0);
        acc1 = fmaf(ex, rf.y, acc1);
      }
    }

    // combine the two edge groups (lane^32 has same channels, other edges)
    acc0 += __shfl_xor(acc0, 32);
    acc1 += __shfl_xor(acc1, 32);
    den += __shfl_xor(den, 32);
    es0 += __shfl_xor(es0, 32);
    es1 += __shfl_xor(es1, 32);
    es2 += __shfl_xor(es2, 32);

    // self loop
    float invd = 1.0f / fmaxf((float)deg, 1.0f);
    float t0 = es0 * invd, t1 = es1 * invd, t2 = es2 * invd;
    float2 xls = __half22float2(xl2p[(size_t)n * 32 + sub]);
    float m0 = xls.x + xrv.x + t0 * w0.x + t1 * w0.y + t2 * w0.z;
    float m1 = xls.y + xrv.y + t0 * w1.x + t1 * w1.y + t2 * w1.z;
    m0 = fmaxf(m0, 0.2f * m0);
    m1 = fmaxf(m1, 0.2f * m1);
    float v = fmaf(m0, w0.w, m1 * w1.w);
    v += __shfl_xor(v, 1);
    v += __shfl_xor(v, 2);
    v += __shfl_xor(v, 4);
    v += __shfl_xor(v, 8);
    v += __shfl_xor(v, 16);  // full 64-ch score (32 lanes x 2 ch)
    float ex = __expf(v);
    den += ex;
    acc0 = fmaf(ex, xls.x, acc0);
    acc1 = fmaf(ex, xls.y, acc1);

    if (grp == 0) {
      float o0 = acc0 / den + bv.x;
      float o1 = acc1 / den + bv.y;
      o0 = o0 > 0.f ? o0 : __expf(o0) - 1.0f;  // ELU
      o1 = o1 > 0.f ? o1 : __expf(o1) - 1.0f;
      *(float2*)&out[(size_t)n * 64 + c0] = make_float2(o0, o1);
    }
  }
}

// ---------------- graph boundaries (batch is sorted) ------------------------
__global__ void gbound_k(const int* __restrict__ batch, int* __restrict__ gstart,
                         int N, int G) {
  int g = blockIdx.x * 256 + threadIdx.x;
  if (g > G) return;
  int lo = 0, hi = N;
  while (lo < hi) {
    int mid = (lo + hi) >> 1;
    if (batch[mid] < g) lo = mid + 1;
    else hi = mid;
  }
  gstart[g] = lo;
}

// ---------------- fused mean-pool + MLP head (block per graph) --------------
__global__ void final_mlp_k(const float* __restrict__ h2, const int* __restrict__ gstart,
                            const float* __restrict__ u, const float* __restrict__ W1,
                            const float* __restrict__ b1, const float* __restrict__ Wh,
                            const float* __restrict__ bh, float* __restrict__ out) {
  __shared__ float feat[65];
  __shared__ float z[32];
  int g = blockIdx.x;
  int t = threadIdx.x;  // 64 threads
  int lo = gstart[g], hi = gstart[g + 1];
  float a = 0.f;
  for (int nn = lo; nn < hi; ++nn) a += h2[(size_t)nn * 64 + t];
  float inv = 1.0f / fmaxf((float)(hi - lo), 1.0f);
  feat[t] = a * inv;
  if (t == 0) feat[64] = u[g];
  __syncthreads();
  if (t < 32) {
    float s = b1[t];
    for (int k = 0; k < 65; ++k) s += feat[k] * W1[t * 65 + k];
    z[t] = fmaxf(s, 0.0f);
  }
  __syncthreads();
  if (t < 10) {
    float s = bh[t];
    for (int k = 0; k < 32; ++k) s += z[k] * Wh[t * 32 + k];
    out[g * 10 + t] = s;
  }
}

// ---------------------------------------------------------------------------
extern "C" void kernel_launch(void* const* d_in, const int* in_sizes, int n_in,
                              void* d_out, int out_size, void* d_ws, size_t ws_size,
                              hipStream_t stream) {
  const float* x      = (const float*)d_in[0];
  const int*   eidx   = (const int*)d_in[1];
  const float* eattr  = (const float*)d_in[2];
  const int*   batch  = (const int*)d_in[3];
  const float* u      = (const float*)d_in[4];
  const float* Wl1    = (const float*)d_in[5];
  const float* bl1    = (const float*)d_in[6];
  const float* Wr1    = (const float*)d_in[7];
  const float* br1    = (const float*)d_in[8];
  const float* We1    = (const float*)d_in[9];
  const float* att1   = (const float*)d_in[10];
  const float* b1     = (const float*)d_in[11];
  const float* Wl2    = (const float*)d_in[12];
  const float* bl2    = (const float*)d_in[13];
  const float* Wr2    = (const float*)d_in[14];
  const float* br2    = (const float*)d_in[15];
  const float* We2    = (const float*)d_in[16];
  const float* att2   = (const float*)d_in[17];
  const float* b2     = (const float*)d_in[18];
  const float* W_lin1 = (const float*)d_in[19];
  const float* b_lin1 = (const float*)d_in[20];
  const float* W_head = (const float*)d_in[21];
  const float* b_head = (const float*)d_in[22];

  const int N = in_sizes[0] / 128;
  const int E = in_sizes[1] / 2;
  const int G = in_sizes[4];
  const int* srcp = eidx;
  const int* dstp = eidx + E;

  // ---- workspace layout ----
  __half* bufh = (__half*)d_ws;                     // xl1 half (N*128) -> xl2 half (N*64)
  float* buf2 = (float*)(bufh + (size_t)N * 128);   // xr1 (N*128) -> xr2 (N*64)
  float* buf3 = buf2 + (size_t)N * 128;             // h1 (N*128) -> h2 (N*64)
  __half* eah = (__half*)(buf3 + (size_t)N * 128);  // E * half4 (8B/edge)
  int* srcs_s = (int*)(eah + (size_t)E * 4);        // E sorted src ids
  int* deg    = srcs_s + E;                         // N
  int* rowptr = deg + N;                            // N+1
  int* cursor = rowptr + N + 1;                     // N
  int* bsum   = cursor + N;                         // 256
  int* gstart = bsum + 256;                         // G+1

  const int nb = (N + 255) / 256;

  // ---- CSR build (sort edges by dst) ----
  hipMemsetAsync(deg, 0, sizeof(int) * (size_t)N, stream);
  hist_k<<<(E + 255) / 256, 256, 0, stream>>>(dstp, deg, E);
  blocksum_k<<<nb, 256, 0, stream>>>(deg, bsum, N);
  scan_bsum_k<<<1, 256, 0, stream>>>(bsum, nb);
  writeptr_k<<<nb, 256, 0, stream>>>(deg, bsum, rowptr, cursor, N, E);
  fill_k<<<(E + 255) / 256, 256, 0, stream>>>(srcp, dstp, eattr, cursor, srcs_s, eah, E);
  gbound_k<<<(G + 256) / 256, 256, 0, stream>>>(batch, gstart, N, G);

  // ---- layer 1 ----
  node_linear2t_k<128><<<(N + 31) / 32, 256, 0, stream>>>(x, Wl1, bl1, Wr1, br1,
                                                          bufh, buf2, N);
  gat1_fused_k<<<2048, 256, 0, stream>>>(rowptr, srcs_s, eah, bufh, buf2,
                                         We1, att1, b1, buf3, N);

  // ---- layer 2 ----
  node_linear2t_k<64><<<(N + 63) / 64, 256, 0, stream>>>(buf3, Wl2, bl2, Wr2, br2,
                                                         bufh, buf2, N);
  gat2_fused_k<<<2048, 256, 0, stream>>>(rowptr, srcs_s, eah, bufh, buf2,
                                         We2, att2, b2, buf3, N);

  // ---- fused pool + head ----
  final_mlp_k<<<G, 64, 0, stream>>>(buf3, gstart, u, W_lin1, b_lin1, W_head, b_head,
                                    (float*)d_out);
}

// Round 11
// 480.529 us; speedup vs baseline: 1.2168x; 1.0410x over previous
//
#include <hip/hip_runtime.h>
#include <hip/hip_fp16.h>
#include <math.h>

// ---------------------------------------------------------------------------
// TacticalGAT round 11 (= r10 + compile fix): packed-fp16 edge math
// (v_pk_add/fma/max_f16 + v_dot2_f32_f16) -- halves per-edge VALU (r9:
// VALUBusy 60% = 65us of f32 issue in gat1).  One 16B edge record
// {src, splat(ea0), splat(ea1), splat(ea2)} -> single dwordx4 load/edge.
// ROCm hip_fp16.h has no __hmax2 -> custom hmax2 via elementwise_max.
// ---------------------------------------------------------------------------

union H2U { __half2 h; unsigned u; };
typedef _Float16 hv2_t __attribute__((ext_vector_type(2)));

__device__ __forceinline__ __half2 hmax2(__half2 a, __half2 b) {
  union { __half2 h; hv2_t v; } x, y, r;
  x.h = a; y.h = b;
  r.v = __builtin_elementwise_max(x.v, y.v);
  return r.h;
}

#if __has_builtin(__builtin_amdgcn_fdot2)
__device__ __forceinline__ float dot2f(__half2 a, __half2 b, float c) {
  union { __half2 h; hv2_t v; } x, y;
  x.h = a; y.h = b;
  return __builtin_amdgcn_fdot2(x.v, y.v, c, false);
}
#else
__device__ __forceinline__ float dot2f(__half2 a, __half2 b, float c) {
  float2 af = __half22float2(a), bf = __half22float2(b);
  return fmaf(af.x, bf.x, fmaf(af.y, bf.y, c));
}
#endif

// ---------------- CSR build -------------------------------------------------
__global__ void hist_k(const int* __restrict__ dst, int* __restrict__ deg, int E) {
  int e = blockIdx.x * 256 + threadIdx.x;
  if (e < E) atomicAdd(&deg[dst[e]], 1);
}

__global__ void blocksum_k(const int* __restrict__ deg, int* __restrict__ bsum, int N) {
  __shared__ int s[256];
  int i = blockIdx.x * 256 + threadIdx.x;
  s[threadIdx.x] = (i < N) ? deg[i] : 0;
  __syncthreads();
  for (int off = 128; off; off >>= 1) {
    if (threadIdx.x < off) s[threadIdx.x] += s[threadIdx.x + off];
    __syncthreads();
  }
  if (threadIdx.x == 0) bsum[blockIdx.x] = s[0];
}

__global__ void scan_bsum_k(int* __restrict__ bsum, int nb) {
  __shared__ int s[256];
  int t = threadIdx.x;
  s[t] = (t < nb) ? bsum[t] : 0;
  __syncthreads();
  for (int off = 1; off < 256; off <<= 1) {
    int v = (t >= off) ? s[t - off] : 0;
    __syncthreads();
    if (t >= off) s[t] += v;
    __syncthreads();
  }
  int excl = (t == 0) ? 0 : s[t - 1];
  if (t < nb) bsum[t] = excl;
}

__global__ void writeptr_k(const int* __restrict__ deg, const int* __restrict__ bsum,
                           int* __restrict__ rowptr, int* __restrict__ cursor, int N, int E) {
  __shared__ int s[256];
  int t = threadIdx.x;
  int i = blockIdx.x * 256 + t;
  s[t] = (i < N) ? deg[i] : 0;
  __syncthreads();
  for (int off = 1; off < 256; off <<= 1) {
    int v = (t >= off) ? s[t - off] : 0;
    __syncthreads();
    if (t >= off) s[t] += v;
    __syncthreads();
  }
  int excl = bsum[blockIdx.x] + ((t == 0) ? 0 : s[t - 1]);
  if (i < N) {
    rowptr[i] = excl;
    cursor[i] = excl;
  }
  if (i == N - 1) rowptr[N] = E;
}

// edge record: {src, splat(ea0), splat(ea1), splat(ea2)} = 16B
__global__ void fill_k(const int* __restrict__ src, const int* __restrict__ dst,
                       const float* __restrict__ eattr, int* __restrict__ cursor,
                       uint4* __restrict__ erec, int E) {
  int e = blockIdx.x * 256 + threadIdx.x;
  if (e >= E) return;
  int d = dst[e];
  int pos = atomicAdd(&cursor[d], 1);
  H2U a0, a1, a2;
  float e0 = eattr[e * 3 + 0], e1 = eattr[e * 3 + 1], e2 = eattr[e * 3 + 2];
  a0.h = __floats2half2_rn(e0, e0);
  a1.h = __floats2half2_rn(e1, e1);
  a2.h = __floats2half2_rn(e2, e2);
  erec[pos] = make_uint4((unsigned)src[e], a0.u, a1.u, a2.u);
}

// ---------------- fused dual node linear, transposed-LDS --------------------
template <int J>
__global__ __launch_bounds__(256, 3) void node_linear2t_k(
    const float* __restrict__ X,
    const float* __restrict__ W1, const float* __restrict__ b1v,
    const float* __restrict__ W2, const float* __restrict__ b2v,
    __half* __restrict__ out1, float* __restrict__ out2, int nrows) {
  constexpr int K = 128, KB = 32;
  constexpr int JG = J / 4;
  constexpr int RG = 256 / JG;
  constexpr int RB = RG * 4;
  constexpr int XP = RB + 4;
  constexpr int WP = J + 4;
  __shared__ float sXT[K][XP];
  __shared__ float sW1T[KB][WP];
  __shared__ float sW2T[KB][WP];

  int tid = threadIdx.x;
  int n0 = blockIdx.x * RB;

  {
    int r = tid & (RB - 1);
    int kq0 = tid / RB;
    constexpr int KQS = 256 / RB;
    int n = n0 + r;
    bool ok = n < nrows;
    for (int kq = kq0; kq < K / 4; kq += KQS) {
      float4 v = ok ? *(const float4*)&X[(size_t)n * K + kq * 4]
                    : make_float4(0.f, 0.f, 0.f, 0.f);
      sXT[kq * 4 + 0][r] = v.x;
      sXT[kq * 4 + 1][r] = v.y;
      sXT[kq * 4 + 2][r] = v.z;
      sXT[kq * 4 + 3][r] = v.w;
    }
  }

  int jg = tid % JG;
  int rg = tid / JG;
  float acc1[4][4] = {}, acc2[4][4] = {};

  for (int kb = 0; kb < K / KB; ++kb) {
    __syncthreads();
    {
      int j = tid & (J - 1);
      int kq0 = tid / J;
      constexpr int KQS = 256 / J;
      for (int kq = kq0; kq < KB / 4; kq += KQS) {
        float4 v1 = *(const float4*)&W1[(size_t)j * K + kb * KB + kq * 4];
        float4 v2 = *(const float4*)&W2[(size_t)j * K + kb * KB + kq * 4];
        sW1T[kq * 4 + 0][j] = v1.x;
        sW1T[kq * 4 + 1][j] = v1.y;
        sW1T[kq * 4 + 2][j] = v1.z;
        sW1T[kq * 4 + 3][j] = v1.w;
        sW2T[kq * 4 + 0][j] = v2.x;
        sW2T[kq * 4 + 1][j] = v2.y;
        sW2T[kq * 4 + 2][j] = v2.z;
        sW2T[kq * 4 + 3][j] = v2.w;
      }
    }
    __syncthreads();
#pragma unroll
    for (int k = 0; k < KB; ++k) {
      float4 xv = *(const float4*)&sXT[kb * KB + k][rg * 4];
      float4 w1 = *(const float4*)&sW1T[k][jg * 4];
      float4 w2 = *(const float4*)&sW2T[k][jg * 4];
      float xs[4] = {xv.x, xv.y, xv.z, xv.w};
      float w1s[4] = {w1.x, w1.y, w1.z, w1.w};
      float w2s[4] = {w2.x, w2.y, w2.z, w2.w};
#pragma unroll
      for (int i = 0; i < 4; ++i)
#pragma unroll
        for (int q = 0; q < 4; ++q) {
          acc1[i][q] = fmaf(xs[i], w1s[q], acc1[i][q]);
          acc2[i][q] = fmaf(xs[i], w2s[q], acc2[i][q]);
        }
    }
  }

  float4 bv1 = *(const float4*)&b1v[jg * 4];
  float4 bv2 = *(const float4*)&b2v[jg * 4];
#pragma unroll
  for (int i = 0; i < 4; ++i) {
    int n = n0 + rg * 4 + i;
    if (n < nrows) {
      H2U a, b;
      a.h = __floats2half2_rn(acc1[i][0] + bv1.x, acc1[i][1] + bv1.y);
      b.h = __floats2half2_rn(acc1[i][2] + bv1.z, acc1[i][3] + bv1.w);
      *(uint2*)&out1[(size_t)n * J + jg * 4] = make_uint2(a.u, b.u);
      float4 o2 = make_float4(acc2[i][0] + bv2.x, acc2[i][1] + bv2.y,
                              acc2[i][2] + bv2.z, acc2[i][3] + bv2.w);
      *(float4*)&out2[(size_t)n * J + jg * 4] = o2;
    }
  }
}

// ---------------- fused GATv2 layer 1 (H=4, C=32, concat) -------------------
// persistent wave per node; lane = channel pair c0=2*lane; packed-fp16 math.
__global__ __launch_bounds__(256) void gat1_fused_k(
    const int* __restrict__ rowptr, const uint4* __restrict__ erec,
    const __half* __restrict__ xlh, const float* __restrict__ xr,
    const float* __restrict__ We, const float* __restrict__ att,
    const float* __restrict__ bias, float* __restrict__ out, int N) {
  constexpr int CH = 8;
  int lane = threadIdx.x & 63;
  int wave0 = __builtin_amdgcn_readfirstlane(
      (int)((blockIdx.x * 256 + threadIdx.x) >> 6));
  int nwaves = gridDim.x * 4;
  const __half2* xl2p = (const __half2*)xlh;
  int c0 = 2 * lane;
  __half2 w0p = __floats2half2_rn(We[c0 * 3 + 0], We[c0 * 3 + 3]);
  __half2 w1p = __floats2half2_rn(We[c0 * 3 + 1], We[c0 * 3 + 4]);
  __half2 w2p = __floats2half2_rn(We[c0 * 3 + 2], We[c0 * 3 + 5]);
  __half2 attp = __floats2half2_rn(att[c0], att[c0 + 1]);
  float2 attf = __half22float2(attp);
  float2 w0f = __half22float2(w0p), w1f = __half22float2(w1p), w2f = __half22float2(w2p);
  __half2 k02 = __floats2half2_rn(0.2f, 0.2f);
  float2 bv = make_float2(bias[c0], bias[c0 + 1]);

  for (int n = wave0; n < N; n += nwaves) {
    float2 xrv = *(const float2*)&xr[(size_t)n * 128 + c0];
    __half2 xrp = __floats2half2_rn(xrv.x, xrv.y);
    int beg = rowptr[n], end = rowptr[n + 1];
    int deg = end - beg;

    float acc0 = 0.f, acc1 = 0.f, den = 0.f;
    __half2 es0h = __floats2half2_rn(0.f, 0.f), es1h = es0h, es2h = es0h;

    int nfull = deg / CH;
    for (int ch = 0; ch < nfull; ++ch) {
      int b = beg + ch * CH;
      uint4 recs[CH];
#pragma unroll
      for (int j = 0; j < CH; ++j) recs[j] = erec[b + j];
      __half2 r_[CH];
#pragma unroll
      for (int j = 0; j < CH; ++j) {
        int s = __builtin_amdgcn_readfirstlane((int)recs[j].x);
        r_[j] = xl2p[(size_t)s * 64 + lane];
      }
#pragma unroll
      for (int j = 0; j < CH; ++j) {
        H2U e0, e1, e2;
        e0.u = recs[j].y; e1.u = recs[j].z; e2.u = recs[j].w;
        es0h = __hadd2(es0h, e0.h);
        es1h = __hadd2(es1h, e1.h);
        es2h = __hadd2(es2h, e2.h);
        __half2 m = __hadd2(r_[j], xrp);
        m = __hfma2(e0.h, w0p, m);
        m = __hfma2(e1.h, w1p, m);
        m = __hfma2(e2.h, w2p, m);
        m = hmax2(m, __hmul2(m, k02));
        float v = dot2f(m, attp, 0.f);
        v += __shfl_xor(v, 1);
        v += __shfl_xor(v, 2);
        v += __shfl_xor(v, 4);
        v += __shfl_xor(v, 8);
        float ex = __expf(v);
        float2 rfF = __half22float2(r_[j]);
        den += ex;
        acc0 = fmaf(ex, rfF.x, acc0);
        acc1 = fmaf(ex, rfF.y, acc1);
      }
    }
    // tail (guarded)
    {
      int b = beg + nfull * CH;
#pragma unroll
      for (int j = 0; j < CH; ++j) {
        int gi = b + j;
        bool valid = gi < end;
        uint4 rec = valid ? erec[gi] : make_uint4((unsigned)n, 0u, 0u, 0u);
        int s = __builtin_amdgcn_readfirstlane((int)rec.x);
        __half2 rf = xl2p[(size_t)s * 64 + lane];
        H2U e0, e1, e2;
        e0.u = rec.y; e1.u = rec.z; e2.u = rec.w;
        es0h = __hadd2(es0h, e0.h);
        es1h = __hadd2(es1h, e1.h);
        es2h = __hadd2(es2h, e2.h);
        __half2 m = __hadd2(rf, xrp);
        m = __hfma2(e0.h, w0p, m);
        m = __hfma2(e1.h, w1p, m);
        m = __hfma2(e2.h, w2p, m);
        m = hmax2(m, __hmul2(m, k02));
        float v = dot2f(m, attp, 0.f);
        v += __shfl_xor(v, 1);
        v += __shfl_xor(v, 2);
        v += __shfl_xor(v, 4);
        v += __shfl_xor(v, 8);
        float ex = valid ? __expf(v) : 0.f;
        float2 rfF = __half22float2(rf);
        den += ex;
        acc0 = fmaf(ex, rfF.x, acc0);
        acc1 = fmaf(ex, rfF.y, acc1);
      }
    }

    // self loop (attr = mean of incoming)
    float invd = 1.0f / fmaxf((float)deg, 1.0f);
    float t0 = __half2float(__low2half(es0h)) * invd;
    float t1 = __half2float(__low2half(es1h)) * invd;
    float t2 = __half2float(__low2half(es2h)) * invd;
    float2 xls = __half22float2(xl2p[(size_t)n * 64 + lane]);
    float m0 = xls.x + xrv.x + t0 * w0f.x + t1 * w1f.x + t2 * w2f.x;
    float m1 = xls.y + xrv.y + t0 * w0f.y + t1 * w1f.y + t2 * w2f.y;
    m0 = fmaxf(m0, 0.2f * m0);
    m1 = fmaxf(m1, 0.2f * m1);
    float v = fmaf(m0, attf.x, m1 * attf.y);
    v += __shfl_xor(v, 1);
    v += __shfl_xor(v, 2);
    v += __shfl_xor(v, 4);
    v += __shfl_xor(v, 8);
    float ex = __expf(v);
    den += ex;
    acc0 = fmaf(ex, xls.x, acc0);
    acc1 = fmaf(ex, xls.y, acc1);

    float o0 = acc0 / den + bv.x;
    float o1 = acc1 / den + bv.y;
    o0 = o0 > 0.f ? o0 : __expf(o0) - 1.0f;  // ELU
    o1 = o1 > 0.f ? o1 : __expf(o1) - 1.0f;
    *(float2*)&out[(size_t)n * 128 + c0] = make_float2(o0, o1);
  }
}

// ---------------- fused GATv2 layer 2 (H=1, C=64, mean) ---------------------
// persistent wave per node; 32-lane edge groups, 2 ch/lane, packed-fp16 math.
__global__ __launch_bounds__(256) void gat2_fused_k(
    const int* __restrict__ rowptr, const uint4* __restrict__ erec,
    const __half* __restrict__ xlh, const float* __restrict__ xr,
    const float* __restrict__ We, const float* __restrict__ att,
    const float* __restrict__ bias, float* __restrict__ out, int N) {
  constexpr int CP = 4;  // edges per group per chunk -> 8 edges/wave/chunk
  int lane = threadIdx.x & 63;
  int wave0 = __builtin_amdgcn_readfirstlane(
      (int)((blockIdx.x * 256 + threadIdx.x) >> 6));
  int nwaves = gridDim.x * 4;
  int sub = lane & 31, grp = lane >> 5;
  int c0 = 2 * sub;
  const __half2* xl2p = (const __half2*)xlh;  // row stride 32 half2
  __half2 w0p = __floats2half2_rn(We[c0 * 3 + 0], We[c0 * 3 + 3]);
  __half2 w1p = __floats2half2_rn(We[c0 * 3 + 1], We[c0 * 3 + 4]);
  __half2 w2p = __floats2half2_rn(We[c0 * 3 + 2], We[c0 * 3 + 5]);
  __half2 attp = __floats2half2_rn(att[c0], att[c0 + 1]);
  float2 attf = __half22float2(attp);
  float2 w0f = __half22float2(w0p), w1f = __half22float2(w1p), w2f = __half22float2(w2p);
  __half2 k02 = __floats2half2_rn(0.2f, 0.2f);
  float2 bv = make_float2(bias[c0], bias[c0 + 1]);

  for (int n = wave0; n < N; n += nwaves) {
    float2 xrv = *(const float2*)&xr[(size_t)n * 64 + c0];
    __half2 xrp = __floats2half2_rn(xrv.x, xrv.y);
    int beg = rowptr[n], end = rowptr[n + 1];
    int deg = end - beg;

    float acc0 = 0.f, acc1 = 0.f, den = 0.f;
    __half2 es0h = __floats2half2_rn(0.f, 0.f), es1h = es0h, es2h = es0h;

    int nfull = deg / (2 * CP);
    int b = beg + grp;
    for (int ch = 0; ch < nfull; ++ch) {
      uint4 recs[CP];
      __half2 r_[CP];
#pragma unroll
      for (int j = 0; j < CP; ++j) recs[j] = erec[b + 2 * j];
#pragma unroll
      for (int j = 0; j < CP; ++j) r_[j] = xl2p[(size_t)recs[j].x * 32 + sub];
#pragma unroll
      for (int j = 0; j < CP; ++j) {
        H2U e0, e1, e2;
        e0.u = recs[j].y; e1.u = recs[j].z; e2.u = recs[j].w;
        es0h = __hadd2(es0h, e0.h);
        es1h = __hadd2(es1h, e1.h);
        es2h = __hadd2(es2h, e2.h);
        __half2 m = __hadd2(r_[j], xrp);
        m = __hfma2(e0.h, w0p, m);
        m = __hfma2(e1.h, w1p, m);
        m = __hfma2(e2.h, w2p, m);
        m = hmax2(m, __hmul2(m, k02));
        float v = dot2f(m, attp, 0.f);
        v += __shfl_xor(v, 1);
        v += __shfl_xor(v, 2);
        v += __shfl_xor(v, 4);
        v += __shfl_xor(v, 8);
        v += __shfl_xor(v, 16);
        float ex = __expf(v);
        float2 rfF = __half22float2(r_[j]);
        den += ex;
        acc0 = fmaf(ex, rfF.x, acc0);
        acc1 = fmaf(ex, rfF.y, acc1);
      }
      b += 2 * CP;
    }
    // tail (guarded)
    {
      int tb = beg + nfull * 2 * CP;
#pragma unroll
      for (int j = 0; j < CP; ++j) {
        int gi = tb + 2 * j + grp;
        bool valid = gi < end;
        uint4 rec = valid ? erec[gi] : make_uint4((unsigned)n, 0u, 0u, 0u);
        __half2 rf = xl2p[(size_t)rec.x * 32 + sub];
        H2U e0, e1, e2;
        e0.u = rec.y; e1.u = rec.z; e2.u = rec.w;
        es0h = __hadd2(es0h, e0.h);
        es1h = __hadd2(es1h, e1.h);
        es2h = __hadd2(es2h, e2.h);
        __half2 m = __hadd2(rf, xrp);
        m = __hfma2(e0.h, w0p, m);
        m = __hfma2(e1.h, w1p, m);
        m = __hfma2(e2.h, w2p, m);
        m = hmax2(m, __hmul2(m, k02));
        float v = dot2f(m, attp, 0.f);
        v += __shfl_xor(v, 1);
        v += __shfl_xor(v, 2);
        v += __shfl_xor(v, 4);
        v += __shfl_xor(v, 8);
        v += __shfl_xor(v, 16);
        float ex = valid ? __expf(v) : 0.f;
        float2 rfF = __half22float2(rf);
        den += ex;
        acc0 = fmaf(ex, rfF.x, acc0);
        acc1 = fmaf(ex, rfF.y, acc1);
      }
    }

    // combine the two edge groups
    float es0 = __half2float(__low2half(es0h));
    float es1 = __half2float(__low2half(es1h));
    float es2 = __half2float(__low2half(es2h));
    acc0 += __shfl_xor(acc0, 32);
    acc1 += __shfl_xor(acc1, 32);
    den += __shfl_xor(den, 32);
    es0 += __shfl_xor(es0, 32);
    es1 += __shfl_xor(es1, 32);
    es2 += __shfl_xor(es2, 32);

    // self loop
    float invd = 1.0f / fmaxf((float)deg, 1.0f);
    float t0 = es0 * invd, t1 = es1 * invd, t2 = es2 * invd;
    float2 xls = __half22float2(xl2p[(size_t)n * 32 + sub]);
    float m0 = xls.x + xrv.x + t0 * w0f.x + t1 * w1f.x + t2 * w2f.x;
    float m1 = xls.y + xrv.y + t0 * w0f.y + t1 * w1f.y + t2 * w2f.y;
    m0 = fmaxf(m0, 0.2f * m0);
    m1 = fmaxf(m1, 0.2f * m1);
    float v = fmaf(m0, attf.x, m1 * attf.y);
    v += __shfl_xor(v, 1);
    v += __shfl_xor(v, 2);
    v += __shfl_xor(v, 4);
    v += __shfl_xor(v, 8);
    v += __shfl_xor(v, 16);
    float ex = __expf(v);
    den += ex;
    acc0 = fmaf(ex, xls.x, acc0);
    acc1 = fmaf(ex, xls.y, acc1);

    if (grp == 0) {
      float o0 = acc0 / den + bv.x;
      float o1 = acc1 / den + bv.y;
      o0 = o0 > 0.f ? o0 : __expf(o0) - 1.0f;  // ELU
      o1 = o1 > 0.f ? o1 : __expf(o1) - 1.0f;
      *(float2*)&out[(size_t)n * 64 + c0] = make_float2(o0, o1);
    }
  }
}

// ---------------- graph boundaries (batch is sorted) ------------------------
__global__ void gbound_k(const int* __restrict__ batch, int* __restrict__ gstart,
                         int N, int G) {
  int g = blockIdx.x * 256 + threadIdx.x;
  if (g > G) return;
  int lo = 0, hi = N;
  while (lo < hi) {
    int mid = (lo + hi) >> 1;
    if (batch[mid] < g) lo = mid + 1;
    else hi = mid;
  }
  gstart[g] = lo;
}

// ---------------- fused mean-pool + MLP head (block per graph) --------------
__global__ void final_mlp_k(const float* __restrict__ h2, const int* __restrict__ gstart,
                            const float* __restrict__ u, const float* __restrict__ W1,
                            const float* __restrict__ b1, const float* __restrict__ Wh,
                            const float* __restrict__ bh, float* __restrict__ out) {
  __shared__ float feat[65];
  __shared__ float z[32];
  int g = blockIdx.x;
  int t = threadIdx.x;  // 64 threads
  int lo = gstart[g], hi = gstart[g + 1];
  float a = 0.f;
  for (int nn = lo; nn < hi; ++nn) a += h2[(size_t)nn * 64 + t];
  float inv = 1.0f / fmaxf((float)(hi - lo), 1.0f);
  feat[t] = a * inv;
  if (t == 0) feat[64] = u[g];
  __syncthreads();
  if (t < 32) {
    float s = b1[t];
    for (int k = 0; k < 65; ++k) s += feat[k] * W1[t * 65 + k];
    z[t] = fmaxf(s, 0.0f);
  }
  __syncthreads();
  if (t < 10) {
    float s = bh[t];
    for (int k = 0; k < 32; ++k) s += z[k] * Wh[t * 32 + k];
    out[g * 10 + t] = s;
  }
}

// ---------------------------------------------------------------------------
extern "C" void kernel_launch(void* const* d_in, const int* in_sizes, int n_in,
                              void* d_out, int out_size, void* d_ws, size_t ws_size,
                              hipStream_t stream) {
  const float* x      = (const float*)d_in[0];
  const int*   eidx   = (const int*)d_in[1];
  const float* eattr  = (const float*)d_in[2];
  const int*   batch  = (const int*)d_in[3];
  const float* u      = (const float*)d_in[4];
  const float* Wl1    = (const float*)d_in[5];
  const float* bl1    = (const float*)d_in[6];
  const float* Wr1    = (const float*)d_in[7];
  const float* br1    = (const float*)d_in[8];
  const float* We1    = (const float*)d_in[9];
  const float* att1   = (const float*)d_in[10];
  const float* b1     = (const float*)d_in[11];
  const float* Wl2    = (const float*)d_in[12];
  const float* bl2    = (const float*)d_in[13];
  const float* Wr2    = (const float*)d_in[14];
  const float* br2    = (const float*)d_in[15];
  const float* We2    = (const float*)d_in[16];
  const float* att2   = (const float*)d_in[17];
  const float* b2     = (const float*)d_in[18];
  const float* W_lin1 = (const float*)d_in[19];
  const float* b_lin1 = (const float*)d_in[20];
  const float* W_head = (const float*)d_in[21];
  const float* b_head = (const float*)d_in[22];

  const int N = in_sizes[0] / 128;
  const int E = in_sizes[1] / 2;
  const int G = in_sizes[4];
  const int* srcp = eidx;
  const int* dstp = eidx + E;

  // ---- workspace layout ----
  __half* bufh = (__half*)d_ws;                     // xl1 half (N*128) -> xl2 half (N*64)
  float* buf2 = (float*)(bufh + (size_t)N * 128);   // xr1 (N*128) -> xr2 (N*64)
  float* buf3 = buf2 + (size_t)N * 128;             // h1 (N*128) -> h2 (N*64)
  uint4* erec = (uint4*)(buf3 + (size_t)N * 128);   // E records (16B)
  int* deg    = (int*)(erec + E);                   // N
  int* rowptr = deg + N;                            // N+1
  int* cursor = rowptr + N + 1;                     // N
  int* bsum   = cursor + N;                         // 256
  int* gstart = bsum + 256;                         // G+1

  const int nb = (N + 255) / 256;

  // ---- CSR build (sort edges by dst) ----
  (void)hipMemsetAsync(deg, 0, sizeof(int) * (size_t)N, stream);
  hist_k<<<(E + 255) / 256, 256, 0, stream>>>(dstp, deg, E);
  blocksum_k<<<nb, 256, 0, stream>>>(deg, bsum, N);
  scan_bsum_k<<<1, 256, 0, stream>>>(bsum, nb);
  writeptr_k<<<nb, 256, 0, stream>>>(deg, bsum, rowptr, cursor, N, E);
  fill_k<<<(E + 255) / 256, 256, 0, stream>>>(srcp, dstp, eattr, cursor, erec, E);
  gbound_k<<<(G + 256) / 256, 256, 0, stream>>>(batch, gstart, N, G);

  // ---- layer 1 ----
  node_linear2t_k<128><<<(N + 31) / 32, 256, 0, stream>>>(x, Wl1, bl1, Wr1, br1,
                                                          bufh, buf2, N);
  gat1_fused_k<<<2048, 256, 0, stream>>>(rowptr, erec, bufh, buf2,
                                         We1, att1, b1, buf3, N);

  // ---- layer 2 ----
  node_linear2t_k<64><<<(N + 63) / 64, 256, 0, stream>>>(buf3, Wl2, bl2, Wr2, br2,
                                                         bufh, buf2, N);
  gat2_fused_k<<<2048, 256, 0, stream>>>(rowptr, erec, bufh, buf2,
                                         We2, att2, b2, buf3, N);

  // ---- fused pool + head ----
  final_mlp_k<<<G, 64, 0, stream>>>(buf3, gstart, u, W_lin1, b_lin1, W_head, b_head,
                                    (float*)d_out);
}